// Round 9
// baseline (213.566 us; speedup 1.0000x reference)
//
#include <hip/hip_runtime.h>
#include <hip/hip_bf16.h>

typedef __attribute__((ext_vector_type(8))) short short8;
typedef __attribute__((ext_vector_type(4))) float f32x4;
typedef __attribute__((ext_vector_type(4))) unsigned short us4;
typedef __attribute__((ext_vector_type(2))) unsigned int u32x2;

#define NE  1024
#define SEQ 2048

__device__ __forceinline__ float bf2f(unsigned short u) {
    union { unsigned u; float f; } x; x.u = ((unsigned)u) << 16; return x.f;
}
__device__ __forceinline__ unsigned short f2bf(float f) {   // RNE
    union { float f; unsigned u; } x; x.f = f;
    unsigned r = x.u + 0x7FFFu + ((x.u >> 16) & 1u);
    return (unsigned short)(r >> 16);
}

// Runtime input-dtype detect (1 = bf16, 0 = f32). Validated rounds 3-7.
__global__ void detect_dtype(const unsigned short* __restrict__ s,
                             int* __restrict__ flag) {
    __shared__ int cnt;
    const int t = threadIdx.x;
    if (t == 0) cnt = 0;
    __syncthreads();
    unsigned short u = s[t];
    int e = (u >> 7) & 0xFF;
    int sane = (e == 0) || (e >= 100 && e <= 140);
    atomicAdd(&cnt, sane);
    __syncthreads();
    if (t == 0) flag[0] = (cnt >= 230) ? 1 : 0;
}

struct Ptrs7 { const void* s[7]; unsigned short* d[7]; };

// One-time f32->bf16 convert (or bf16 copy) of q,k,v (z<3) and weights (z>=3).
__global__ void convert7(Ptrs7 p, const int* __restrict__ flag, int zoff) {
    const int z = blockIdx.z + zoff;
    const int n = (z < 3) ? (4 << 20) : (1 << 20);
    const bool in_f32 = (flag[0] == 0);
    unsigned short* d = p.d[z];
    const int stride = gridDim.x * blockDim.x;
    for (int i8 = blockIdx.x * blockDim.x + threadIdx.x; i8 * 8 < n; i8 += stride) {
        size_t off = (size_t)i8 * 8;
        if (in_f32) {
            const float* sp = (const float*)p.s[z] + off;
            float4 a = *(const float4*)sp, b2 = *(const float4*)(sp + 4);
            short8 sv;
            sv[0] = (short)f2bf(a.x);  sv[1] = (short)f2bf(a.y);
            sv[2] = (short)f2bf(a.z);  sv[3] = (short)f2bf(a.w);
            sv[4] = (short)f2bf(b2.x); sv[5] = (short)f2bf(b2.y);
            sv[6] = (short)f2bf(b2.z); sv[7] = (short)f2bf(b2.w);
            *(short8*)(d + off) = sv;
        } else {
            *(short8*)(d + off) = *(const short8*)((const unsigned short*)p.s[z] + off);
        }
    }
}

// m97-structure GEMM: C[M][1024] = A @ W^T (+bias). 128xTN tile, BK=32,
// 256 threads = 4 waves. TN=128: wave=64x64 (proj, 768 blocks = 3/CU).
// TN=64: wave=64x32 (output GEMM -> 512 blocks = 2 blocks/CU).
// R10: XCD-aware bijective tile remap (T1): each XCD gets a contiguous tile
// chunk -> its A-panels + W stay L2-resident (validated R3/R5: FETCH 101->37MB).
// VT: z==2 writes V transposed per head into vt[b][h][d][s]. Validated R7.
template<int AWS, int WWS, int OUTF, int VT, int TN = 128>
__global__ __launch_bounds__(256, 3)
void gemm_bt(const void* A0, const void* A1, const void* A2,
             const void* W0, const void* W1, const void* W2,
             const void* b0, const void* b1, const void* b2,
             void* C0, void* C1, void* C2,
             const int* __restrict__ flag)
{
    constexpr int NT = TN / 32;          // n-tiles of 16 per wave
    constexpr int NX = NE / TN;          // grid x extent (8 or 16)
    constexpr int PER = NX * 32 / 8;     // tiles per XCD (gridDim.y == 32)
    __shared__ __align__(16) unsigned short As[128 * 32];
    __shared__ __align__(16) unsigned short Bs[TN * 32];
    const int z = blockIdx.z;
    const void* Ap = (z == 0) ? A0 : (z == 1) ? A1 : A2;
    const void* Wp = (z == 0) ? W0 : (z == 1) ? W1 : W2;
    const void* bp = (z == 0) ? b0 : (z == 1) ? b1 : b2;
    void*       Cp = (z == 0) ? C0 : (z == 1) ? C1 : C2;
    const bool in_f32 = (flag[0] == 0);
    const int t = threadIdx.x;
    const int w = t >> 6, l = t & 63, q = l >> 4, n = l & 15;
    // --- T1 XCD swizzle: lin%8 ~ XCD id; give each XCD contiguous tiles ---
    const int lin2 = blockIdx.x + NX * blockIdx.y;
    const int tidx = (lin2 & 7) * PER + (lin2 >> 3);
    const int m0 = (tidx / NX) * 128, n0 = (tidx % NX) * TN;
    const int wm = (w >> 1) * 64, wn = (w & 1) * (TN / 2);
    const int srow = t >> 2, sk = (t & 3) * 8;

    f32x4 acc[4][NT] = {};

    for (int k0 = 0; k0 < NE; k0 += 32) {
        if (AWS || !in_f32) {
            #pragma unroll
            for (int hh = 0; hh < 2; hh++) {
                const unsigned short* ga = (const unsigned short*)Ap +
                    (size_t)(m0 + srow + hh * 64) * NE + k0 + sk;
                __builtin_amdgcn_global_load_lds(
                    (const __attribute__((address_space(1))) void*)ga,
                    (__attribute__((address_space(3))) void*)&As[hh * 2048 + w * 512],
                    16, 0, 0);
            }
        } else {
            #pragma unroll
            for (int hh = 0; hh < 2; hh++) {
                const float* a = (const float*)Ap +
                                 (size_t)(m0 + srow + hh * 64) * NE + k0 + sk;
                float4 x0 = *(const float4*)a, x1 = *(const float4*)(a + 4);
                short8 sv;
                sv[0] = (short)f2bf(x0.x); sv[1] = (short)f2bf(x0.y);
                sv[2] = (short)f2bf(x0.z); sv[3] = (short)f2bf(x0.w);
                sv[4] = (short)f2bf(x1.x); sv[5] = (short)f2bf(x1.y);
                sv[6] = (short)f2bf(x1.z); sv[7] = (short)f2bf(x1.w);
                *(short8*)(&As[hh * 2048 + t * 8]) = sv;
            }
        }
        if (WWS || !in_f32) {
            #pragma unroll
            for (int hh = 0; hh < TN / 64; hh++) {
                const unsigned short* ga = (const unsigned short*)Wp +
                    (size_t)(n0 + srow + hh * 64) * NE + k0 + sk;
                __builtin_amdgcn_global_load_lds(
                    (const __attribute__((address_space(1))) void*)ga,
                    (__attribute__((address_space(3))) void*)&Bs[hh * 2048 + w * 512],
                    16, 0, 0);
            }
        } else {
            #pragma unroll
            for (int hh = 0; hh < TN / 64; hh++) {
                const float* a = (const float*)Wp +
                                 (size_t)(n0 + srow + hh * 64) * NE + k0 + sk;
                float4 x0 = *(const float4*)a, x1 = *(const float4*)(a + 4);
                short8 sv;
                sv[0] = (short)f2bf(x0.x); sv[1] = (short)f2bf(x0.y);
                sv[2] = (short)f2bf(x0.z); sv[3] = (short)f2bf(x0.w);
                sv[4] = (short)f2bf(x1.x); sv[5] = (short)f2bf(x1.y);
                sv[6] = (short)f2bf(x1.z); sv[7] = (short)f2bf(x1.w);
                *(short8*)(&Bs[hh * 2048 + t * 8]) = sv;
            }
        }
        __syncthreads();

        short8 af[4], bfv[NT];
        #pragma unroll
        for (int mt = 0; mt < 4; mt++)
            af[mt] = *(const short8*)(&As[(wm + mt * 16 + n) * 32 + q * 8]);
        #pragma unroll
        for (int nt = 0; nt < NT; nt++)
            bfv[nt] = *(const short8*)(&Bs[(wn + nt * 16 + n) * 32 + q * 8]);
        #pragma unroll
        for (int mt = 0; mt < 4; mt++)
            #pragma unroll
            for (int nt = 0; nt < NT; nt++)
                acc[mt][nt] = __builtin_amdgcn_mfma_f32_16x16x32_bf16(
                    af[mt], bfv[nt], acc[mt][nt], 0, 0, 0);
        __syncthreads();
    }

    #pragma unroll
    for (int mt = 0; mt < 4; mt++)
        #pragma unroll
        for (int nt = 0; nt < NT; nt++) {
            int row0 = m0 + wm + mt * 16 + q * 4;
            int col  = n0 + wn + nt * 16 + n;
            float bia = 0.f;
            if (bp)
                bia = in_f32 ? ((const float*)bp)[col]
                             : bf2f(((const unsigned short*)bp)[col]);
            if (VT && z == 2) {
                // vt[b][h][d][s]; r=0..3 -> consecutive s -> one b64 store
                int bb = row0 >> 11, s0 = row0 & 2047;
                int hh2 = col >> 6, dd = col & 63;
                us4 pk4;
                #pragma unroll
                for (int r = 0; r < 4; r++)
                    pk4[r] = f2bf(acc[mt][nt][r] + bia);
                *(us4*)((unsigned short*)Cp +
                        ((size_t)((bb * 16 + hh2) * 64 + dd) << 11) + s0) = pk4;
            } else {
                #pragma unroll
                for (int r = 0; r < 4; r++) {
                    float v2 = acc[mt][nt][r] + bia;
                    size_t idx = (size_t)(row0 + r) * NE + col;
                    if (OUTF && in_f32) ((float*)Cp)[idx] = v2;
                    else                ((unsigned short*)Cp)[idx] = f2bf(v2);
                }
            }
        }
}

// Flash-style causal attention — R16 = R12 compute structure (validated, 43.7us)
// + XCD-aware (b,h) grouping:
//  * R15 widening REVERTED (8->4 waves/block cut occupancy 25->15%, +10.6us:
//    kernel needs >=4 waves/SIMD TLP to hide the per-iter dependency chain).
//  * NEW (T1): hardware XCD = lin%8 = blockIdx.x%8 = g. Old mapping put all
//    32 (b,h) K/V slices (16 MB) through each XCD's 4 MB L2. Remap so XCD g
//    owns bh in {4g..4g+3}: per-XCD K/V footprint 2 MB -> L2-resident.
//    Bijection: b=g>>2, h=(g&3)*4+(y&3), base=(y>>2)|((x>>3)<<2),
//    qb = z ? 15-base : base — preserves the z-flip pairing exactly
//    (co-resident blocks still sum to 34 iterations).
//  * 16x16x32 MFMA, swapped QK^T, cvt_pk P-pack, single barrier/iter,
//    K/V LDS double-buffer + 2-deep reg prefetch, T15 deferred-PV, setprio.
// 512 threads = 8 waves x 16 rows. Grid (16,16,2) = 512 blocks = 2 blocks/CU.
// ctx may alias qh: block reads only the q-rows it later writes.
__global__ __launch_bounds__(512, 4)
void attn(const unsigned short* qh, const unsigned short* kh,
          const unsigned short* vt, unsigned short* ctx)
{
    __shared__ __align__(16) unsigned short Ks[2][64 * 72];    // [buf][j][d], pad 72
    __shared__ __align__(16) unsigned short Vt[2][64 * 72];    // [buf][d][j], pad 72
    __shared__ __align__(16) unsigned short Ps[8][16 * 72];    // per-wave P, [i][j]
    const int t = threadIdx.x, w = t >> 6, l = t & 63;
    const int q = l >> 4, n = l & 15;
    const int half = w >> 2;
    // --- T1 XCD (b,h) grouping: XCD g = x%8 owns bh in {4g..4g+3} ---
    const int g = blockIdx.x & 7;
    const int b = g >> 2;
    const int h = (g & 3) * 4 + (blockIdx.y & 3);
    const int base_q = (blockIdx.y >> 2) | ((blockIdx.x >> 3) << 2);
    const int qb = blockIdx.z ? (15 - base_q) : base_q;  // z-flip: CU pair = 34 iters
    const int jtmax = 2 * qb + 1;        // block's last K/V tile
    const int qbe = 2 * qb + half;       // this wave's diag (last compute) tile
    const size_t base = (size_t)b * SEQ * NE + h * 64;
    const size_t vbase = (size_t)((b * 16 + h) * 64) << 11;   // vt[b][h][0][0]
    const int i0 = qb * 128 + w * 16;    // wave's 16 q-rows

    short8 qf[2];
    qf[0] = *(const short8*)(&qh[base + (size_t)(i0 + n) * NE + q * 8]);
    qf[1] = *(const short8*)(&qh[base + (size_t)(i0 + n) * NE + 32 + q * 8]);

    f32x4 o[4] = {};
    float lsp[4] = {0.f, 0.f, 0.f, 0.f};
    short8 pf_prev[2];     // previous tile's P fragments
    short8 vf_prev[8];     // previous tile's V fragments [ks*4+dt]

    const float K1 = 0.125f * 1.4426950408889634f;
    const float B2 = 24.0f * 1.4426950408889634f;

    // staging maps: 512 b128 chunks each for K and V^T, 1 per thread
    const int kr = t >> 3, kc = (t & 7) * 8;           // K: [row][8col]
    const int vd = t >> 3, vj = (t & 7) * 8;           // V^T: [d][8j]

    // prologue: tile 0 -> buf 0, prefetch tile 1 into regs (jtmax >= 1 always)
    short8 pk, pv;
    pk = *(const short8*)(&kh[base + (size_t)kr * NE + kc]);
    pv = *(const short8*)(&vt[vbase + ((size_t)vd << 11) + vj]);
    *(short8*)(&Ks[0][kr * 72 + kc]) = pk;
    *(short8*)(&Vt[0][vd * 72 + vj]) = pv;
    pk = *(const short8*)(&kh[base + (size_t)(64 + kr) * NE + kc]);
    pv = *(const short8*)(&vt[vbase + ((size_t)vd << 11) + 64 + vj]);
    __syncthreads();

    unsigned short* PsW = &Ps[w][0];
    int cur = 0;

    for (int jt = 0; jt <= jtmax; jt++) {
        // ---- drain prefetch regs (tile jt+1) into the idle buffer ----
        if (jt + 1 <= jtmax) {
            *(short8*)(&Ks[cur ^ 1][kr * 72 + kc]) = pk;
            *(short8*)(&Vt[cur ^ 1][vd * 72 + vj]) = pv;
        }
        // ---- issue tile jt+2 global loads (overlap with compute) ----
        if (jt + 2 <= jtmax) {
            const int jn = (jt + 2) * 64;
            pk = *(const short8*)(&kh[base + (size_t)(jn + kr) * NE + kc]);
            pv = *(const short8*)(&vt[vbase + ((size_t)vd << 11) + jn + vj]);
        }

        if (jt <= qbe) {    // wave-uniform; waves 0-3 skip the final tile
            const unsigned short* Kc = &Ks[cur][0];
            const unsigned short* Vc = &Vt[cur][0];

            // issue K-fragment reads first...
            short8 kf[2][4];
            #pragma unroll
            for (int ks = 0; ks < 2; ks++)
                #pragma unroll
                for (int nt = 0; nt < 4; nt++)
                    kf[ks][nt] = *(const short8*)(&Kc[(nt * 16 + n) * 72 + ks * 32 + q * 8]);

            // ...then the deferred PV of tile jt-1 (register-only; overlaps
            // the ds_read latency above on the MFMA pipe)
            if (jt > 0) {
                __builtin_amdgcn_s_setprio(1);
                #pragma unroll
                for (int ks = 0; ks < 2; ks++)
                    #pragma unroll
                    for (int dt = 0; dt < 4; dt++)
                        o[dt] = __builtin_amdgcn_mfma_f32_16x16x32_bf16(
                            pf_prev[ks], vf_prev[ks * 4 + dt], o[dt], 0, 0, 0);
                __builtin_amdgcn_s_setprio(0);
            }

            f32x4 sa[4] = {};
            __builtin_amdgcn_s_setprio(1);
            #pragma unroll
            for (int ks = 0; ks < 2; ks++)
                #pragma unroll
                for (int nt = 0; nt < 4; nt++)
                    // swapped: rows = j (k-index), cols = i (q-row)
                    sa[nt] = __builtin_amdgcn_mfma_f32_16x16x32_bf16(
                        kf[ks][nt], qf[ks], sa[nt], 0, 0, 0);
            __builtin_amdgcn_s_setprio(0);

            const bool diag = (jt == qbe);
            const int i = i0 + n;
            #pragma unroll
            for (int nt = 0; nt < 4; nt++) {
                float p[4];
                #pragma unroll
                for (int r = 0; r < 4; r++) {
                    float e = fmaf(sa[nt][r], K1, -B2);
                    if (diag) {
                        int j = jt * 64 + nt * 16 + q * 4 + r;
                        bool ok = (j < i) || (i == 0 && j == 0);
                        e = ok ? e : -256.0f;      // exp2(-256) == 0 exactly
                    }
                    p[r] = __builtin_amdgcn_exp2f(e);
                }
                lsp[nt] += (p[0] + p[1]) + (p[2] + p[3]);
                unsigned w0, w1;
                asm("v_cvt_pk_bf16_f32 %0, %1, %2" : "=v"(w0) : "v"(p[0]), "v"(p[1]));
                asm("v_cvt_pk_bf16_f32 %0, %1, %2" : "=v"(w1) : "v"(p[2]), "v"(p[3]));
                u32x2 wv; wv[0] = w0; wv[1] = w1;
                // P[i=n][j = nt*16 + q*4 .. +3] — one b64 per nt
                *(u32x2*)(&PsW[n * 72 + nt * 16 + q * 4]) = wv;
            }
            asm volatile("s_waitcnt lgkmcnt(0)" ::: "memory"); // Ps write->read (wave-private)

            // load NEXT-iteration operands: P frags + V frags into registers
            #pragma unroll
            for (int ks = 0; ks < 2; ks++)
                pf_prev[ks] = *(const short8*)(&PsW[n * 72 + ks * 32 + q * 8]);
            #pragma unroll
            for (int ks = 0; ks < 2; ks++)
                #pragma unroll
                for (int dt = 0; dt < 4; dt++)
                    vf_prev[ks * 4 + dt] =
                        *(const short8*)(&Vc[(dt * 16 + n) * 72 + ks * 32 + q * 8]);
        } else if (jt == qbe + 1) {
            // waves 0-3 flush their diag tile here (qbe+1 == jtmax)
            __builtin_amdgcn_s_setprio(1);
            #pragma unroll
            for (int ks = 0; ks < 2; ks++)
                #pragma unroll
                for (int dt = 0; dt < 4; dt++)
                    o[dt] = __builtin_amdgcn_mfma_f32_16x16x32_bf16(
                        pf_prev[ks], vf_prev[ks * 4 + dt], o[dt], 0, 0, 0);
            __builtin_amdgcn_s_setprio(0);
        }
        __syncthreads();   // single barrier: protects both buffers across swap
        cur ^= 1;
    }

    if (half) {   // waves 4-7 flush the final tile after the loop
        #pragma unroll
        for (int ks = 0; ks < 2; ks++)
            #pragma unroll
            for (int dt = 0; dt < 4; dt++)
                o[dt] = __builtin_amdgcn_mfma_f32_16x16x32_bf16(
                    pf_prev[ks], vf_prev[ks * 4 + dt], o[dt], 0, 0, 0);
    }

    // row sums: lane holds partial for row i = i0 + n; reduce across q-groups
    float ls = (lsp[0] + lsp[1]) + (lsp[2] + lsp[3]);
    ls += __shfl_xor(ls, 16, 64);
    ls += __shfl_xor(ls, 32, 64);

    #pragma unroll
    for (int r = 0; r < 4; r++) {
        float inv = 1.0f / __shfl(ls, q * 4 + r, 64);   // total for row i0+q*4+r
        #pragma unroll
        for (int dt = 0; dt < 4; dt++)
            ctx[base + (size_t)(i0 + q * 4 + r) * NE + dt * 16 + n] =
                f2bf(o[dt][r] * inv);
    }
}

extern "C" void kernel_launch(void* const* d_in, const int* in_sizes, int n_in,
                              void* d_out, int out_size, void* d_ws, size_t ws_size,
                              hipStream_t stream) {
    const void* q  = d_in[0];
    const void* k  = d_in[1];
    const void* v  = d_in[2];
    const void* Wq = d_in[3];
    const void* Wk = d_in[4];
    const void* Wv = d_in[5];
    const void* bv = d_in[6];
    const void* Wo = d_in[7];
    const void* bo = d_in[8];

    const size_t MB = 1024 * 1024;
    const size_t M4 = 4 * MB;   // 4M shorts = 8 MB
    unsigned short* ws = (unsigned short*)d_ws;
    unsigned short* qh  = ws;               // [2,2048,1024] bf16
    unsigned short* kh  = ws + 1 * M4;      // [2,2048,1024] bf16
    unsigned short* vt  = ws + 2 * M4;      // [2,16,64,2048] bf16 (V transposed)
    unsigned short* ctx = qh;               // safe alias (see attn)

    int tier = (ws_size >= 56 * MB + 64) ? 2 : (ws_size >= 32 * MB + 64) ? 1 : 0;

    unsigned short *qc, *kc, *vc, *Wqc, *Wkc, *Wvc, *Woc;
    int* flag;
    if (tier == 2) {
        qc = ws + 3 * M4; kc = ws + 4 * M4; vc = ws + 5 * M4;
        Wqc = ws + 6 * M4;           Wkc = Wqc + 1 * MB;
        Wvc = Wqc + 2 * MB;          Woc = Wqc + 3 * MB;
        flag = (int*)((char*)d_ws + 56 * MB);
    } else if (tier == 1) {
        qc = kc = vc = nullptr;
        Wqc = ws + 3 * M4;           Wkc = Wqc + 1 * MB;
        Wvc = Wqc + 2 * MB;          Woc = Wqc + 3 * MB;
        flag = (int*)((char*)d_ws + 32 * MB);
    } else {
        qc = kc = vc = nullptr; Wqc = Wkc = Wvc = Woc = nullptr;
        flag = (int*)((char*)d_ws + 24 * MB);
    }

    detect_dtype<<<1, 256, 0, stream>>>((const unsigned short*)q, flag);

    if (tier > 0) {
        Ptrs7 p;
        p.s[0] = q;  p.s[1] = k;  p.s[2] = v;
        p.s[3] = Wq; p.s[4] = Wk; p.s[5] = Wv; p.s[6] = Wo;
        p.d[0] = qc; p.d[1] = kc; p.d[2] = vc;
        p.d[3] = Wqc; p.d[4] = Wkc; p.d[5] = Wvc; p.d[6] = Woc;
        if (tier == 2)
            convert7<<<dim3(1024, 1, 7), 256, 0, stream>>>(p, flag, 0);
        else
            convert7<<<dim3(1024, 1, 4), 256, 0, stream>>>(p, flag, 3);
    }

    if (tier == 2)
        gemm_bt<1, 1, 0, 1><<<dim3(8, 32, 3), 256, 0, stream>>>(
            qc, kc, vc, Wqc, Wkc, Wvc, nullptr, nullptr, bv, qh, kh, vt, flag);
    else if (tier == 1)
        gemm_bt<0, 1, 0, 1><<<dim3(8, 32, 3), 256, 0, stream>>>(
            q, k, v, Wqc, Wkc, Wvc, nullptr, nullptr, bv, qh, kh, vt, flag);
    else
        gemm_bt<0, 0, 0, 1><<<dim3(8, 32, 3), 256, 0, stream>>>(
            q, k, v, Wq, Wk, Wv, nullptr, nullptr, bv, qh, kh, vt, flag);

    attn<<<dim3(16, 16, 2), 512, 0, stream>>>(qh, kh, vt, ctx);

    // output GEMM: TN=64 tiles -> 512 blocks = 2 blocks/CU (drain coverage)
    if (tier > 0)
        gemm_bt<1, 1, 1, 0, 64><<<dim3(16, 32, 1), 256, 0, stream>>>(
            ctx, ctx, ctx, Woc, Woc, Woc, bo, bo, bo, d_out, d_out, d_out, flag);
    else
        gemm_bt<1, 0, 1, 0, 64><<<dim3(16, 32, 1), 256, 0, stream>>>(
            ctx, ctx, ctx, Wo, Wo, Wo, bo, bo, bo, d_out, d_out, d_out, flag);
}

// Round 10
// 210.057 us; speedup vs baseline: 1.0167x; 1.0167x over previous
//
#include <hip/hip_runtime.h>
#include <hip/hip_bf16.h>

typedef __attribute__((ext_vector_type(8))) short short8;
typedef __attribute__((ext_vector_type(4))) float f32x4;
typedef __attribute__((ext_vector_type(4))) unsigned short us4;
typedef __attribute__((ext_vector_type(2))) unsigned int u32x2;

#define NE  1024
#define SEQ 2048

__device__ __forceinline__ float bf2f(unsigned short u) {
    union { unsigned u; float f; } x; x.u = ((unsigned)u) << 16; return x.f;
}
__device__ __forceinline__ unsigned short f2bf(float f) {   // RNE
    union { float f; unsigned u; } x; x.f = f;
    unsigned r = x.u + 0x7FFFu + ((x.u >> 16) & 1u);
    return (unsigned short)(r >> 16);
}

// Runtime input-dtype detect (1 = bf16, 0 = f32). Validated rounds 3-7.
__global__ void detect_dtype(const unsigned short* __restrict__ s,
                             int* __restrict__ flag) {
    __shared__ int cnt;
    const int t = threadIdx.x;
    if (t == 0) cnt = 0;
    __syncthreads();
    unsigned short u = s[t];
    int e = (u >> 7) & 0xFF;
    int sane = (e == 0) || (e >= 100 && e <= 140);
    atomicAdd(&cnt, sane);
    __syncthreads();
    if (t == 0) flag[0] = (cnt >= 230) ? 1 : 0;
}

struct Ptrs7 { const void* s[7]; unsigned short* d[7]; };

// One-time f32->bf16 convert (or bf16 copy) of q,k,v (z<3) and weights (z>=3).
__global__ void convert7(Ptrs7 p, const int* __restrict__ flag, int zoff) {
    const int z = blockIdx.z + zoff;
    const int n = (z < 3) ? (4 << 20) : (1 << 20);
    const bool in_f32 = (flag[0] == 0);
    unsigned short* d = p.d[z];
    const int stride = gridDim.x * blockDim.x;
    for (int i8 = blockIdx.x * blockDim.x + threadIdx.x; i8 * 8 < n; i8 += stride) {
        size_t off = (size_t)i8 * 8;
        if (in_f32) {
            const float* sp = (const float*)p.s[z] + off;
            float4 a = *(const float4*)sp, b2 = *(const float4*)(sp + 4);
            short8 sv;
            sv[0] = (short)f2bf(a.x);  sv[1] = (short)f2bf(a.y);
            sv[2] = (short)f2bf(a.z);  sv[3] = (short)f2bf(a.w);
            sv[4] = (short)f2bf(b2.x); sv[5] = (short)f2bf(b2.y);
            sv[6] = (short)f2bf(b2.z); sv[7] = (short)f2bf(b2.w);
            *(short8*)(d + off) = sv;
        } else {
            *(short8*)(d + off) = *(const short8*)((const unsigned short*)p.s[z] + off);
        }
    }
}

// m97-structure GEMM: C[M][1024] = A @ W^T (+bias). TMxTN tile, BK=32,
// 256 threads = 4 waves (wave = (TM/2)x(TN/2)).
//  * proj: TM=128,TN=128, grid (8,32,3) = 768 blocks = 3/CU.
//  * out (R17): TM=64,TN=64, grid (16,64,1) = 1024 blocks = 4 blocks/CU —
//    latency-bound structure, more resident blocks cover the staging/barrier
//    drain (R1's 1->2 blocks/CU retile was worth ~8 us end-to-end).
// T1 XCD-aware bijective tile remap: each XCD gets a contiguous tile chunk ->
// its A-panels + W stay L2-resident (validated R3/R5: FETCH 101->37MB).
// VT: z==2 writes V transposed per head into vt[b][h][d][s]. Validated R7.
template<int AWS, int WWS, int OUTF, int VT, int TN = 128, int TM = 128, int WPE = 3>
__global__ __launch_bounds__(256, WPE)
void gemm_bt(const void* A0, const void* A1, const void* A2,
             const void* W0, const void* W1, const void* W2,
             const void* b0, const void* b1, const void* b2,
             void* C0, void* C1, void* C2,
             const int* __restrict__ flag)
{
    constexpr int NT = TN / 32;          // n-tiles of 16 per wave
    constexpr int MT = TM / 32;          // m-tiles of 16 per wave
    constexpr int NX = NE / TN;          // grid x extent
    constexpr int GY = 4096 / TM;        // grid y extent
    constexpr int PER = NX * GY / 8;     // tiles per XCD
    __shared__ __align__(16) unsigned short As[TM * 32];
    __shared__ __align__(16) unsigned short Bs[TN * 32];
    const int z = blockIdx.z;
    const void* Ap = (z == 0) ? A0 : (z == 1) ? A1 : A2;
    const void* Wp = (z == 0) ? W0 : (z == 1) ? W1 : W2;
    const void* bp = (z == 0) ? b0 : (z == 1) ? b1 : b2;
    void*       Cp = (z == 0) ? C0 : (z == 1) ? C1 : C2;
    const bool in_f32 = (flag[0] == 0);
    const int t = threadIdx.x;
    const int w = t >> 6, l = t & 63, q = l >> 4, n = l & 15;
    // --- T1 XCD swizzle: lin%8 ~ XCD id; give each XCD contiguous tiles ---
    const int lin2 = blockIdx.x + NX * blockIdx.y;
    const int tidx = (lin2 & 7) * PER + (lin2 >> 3);
    const int m0 = (tidx / NX) * TM, n0 = (tidx % NX) * TN;
    const int wm = (w >> 1) * (TM / 2), wn = (w & 1) * (TN / 2);
    const int srow = t >> 2, sk = (t & 3) * 8;

    f32x4 acc[MT][NT] = {};

    for (int k0 = 0; k0 < NE; k0 += 32) {
        if (AWS || !in_f32) {
            #pragma unroll
            for (int hh = 0; hh < TM / 64; hh++) {
                const unsigned short* ga = (const unsigned short*)Ap +
                    (size_t)(m0 + srow + hh * 64) * NE + k0 + sk;
                __builtin_amdgcn_global_load_lds(
                    (const __attribute__((address_space(1))) void*)ga,
                    (__attribute__((address_space(3))) void*)&As[hh * 2048 + w * 512],
                    16, 0, 0);
            }
        } else {
            #pragma unroll
            for (int hh = 0; hh < TM / 64; hh++) {
                const float* a = (const float*)Ap +
                                 (size_t)(m0 + srow + hh * 64) * NE + k0 + sk;
                float4 x0 = *(const float4*)a, x1 = *(const float4*)(a + 4);
                short8 sv;
                sv[0] = (short)f2bf(x0.x); sv[1] = (short)f2bf(x0.y);
                sv[2] = (short)f2bf(x0.z); sv[3] = (short)f2bf(x0.w);
                sv[4] = (short)f2bf(x1.x); sv[5] = (short)f2bf(x1.y);
                sv[6] = (short)f2bf(x1.z); sv[7] = (short)f2bf(x1.w);
                *(short8*)(&As[hh * 2048 + t * 8]) = sv;
            }
        }
        if (WWS || !in_f32) {
            #pragma unroll
            for (int hh = 0; hh < TN / 64; hh++) {
                const unsigned short* ga = (const unsigned short*)Wp +
                    (size_t)(n0 + srow + hh * 64) * NE + k0 + sk;
                __builtin_amdgcn_global_load_lds(
                    (const __attribute__((address_space(1))) void*)ga,
                    (__attribute__((address_space(3))) void*)&Bs[hh * 2048 + w * 512],
                    16, 0, 0);
            }
        } else {
            #pragma unroll
            for (int hh = 0; hh < TN / 64; hh++) {
                const float* a = (const float*)Wp +
                                 (size_t)(n0 + srow + hh * 64) * NE + k0 + sk;
                float4 x0 = *(const float4*)a, x1 = *(const float4*)(a + 4);
                short8 sv;
                sv[0] = (short)f2bf(x0.x); sv[1] = (short)f2bf(x0.y);
                sv[2] = (short)f2bf(x0.z); sv[3] = (short)f2bf(x0.w);
                sv[4] = (short)f2bf(x1.x); sv[5] = (short)f2bf(x1.y);
                sv[6] = (short)f2bf(x1.z); sv[7] = (short)f2bf(x1.w);
                *(short8*)(&Bs[hh * 2048 + t * 8]) = sv;
            }
        }
        __syncthreads();

        short8 af[MT], bfv[NT];
        #pragma unroll
        for (int mt = 0; mt < MT; mt++)
            af[mt] = *(const short8*)(&As[(wm + mt * 16 + n) * 32 + q * 8]);
        #pragma unroll
        for (int nt = 0; nt < NT; nt++)
            bfv[nt] = *(const short8*)(&Bs[(wn + nt * 16 + n) * 32 + q * 8]);
        #pragma unroll
        for (int mt = 0; mt < MT; mt++)
            #pragma unroll
            for (int nt = 0; nt < NT; nt++)
                acc[mt][nt] = __builtin_amdgcn_mfma_f32_16x16x32_bf16(
                    af[mt], bfv[nt], acc[mt][nt], 0, 0, 0);
        __syncthreads();
    }

    #pragma unroll
    for (int mt = 0; mt < MT; mt++)
        #pragma unroll
        for (int nt = 0; nt < NT; nt++) {
            int row0 = m0 + wm + mt * 16 + q * 4;
            int col  = n0 + wn + nt * 16 + n;
            float bia = 0.f;
            if (bp)
                bia = in_f32 ? ((const float*)bp)[col]
                             : bf2f(((const unsigned short*)bp)[col]);
            if (VT && z == 2) {
                // vt[b][h][d][s]; r=0..3 -> consecutive s -> one b64 store
                int bb = row0 >> 11, s0 = row0 & 2047;
                int hh2 = col >> 6, dd = col & 63;
                us4 pk4;
                #pragma unroll
                for (int r = 0; r < 4; r++)
                    pk4[r] = f2bf(acc[mt][nt][r] + bia);
                *(us4*)((unsigned short*)Cp +
                        ((size_t)((bb * 16 + hh2) * 64 + dd) << 11) + s0) = pk4;
            } else {
                #pragma unroll
                for (int r = 0; r < 4; r++) {
                    float v2 = acc[mt][nt][r] + bia;
                    size_t idx = (size_t)(row0 + r) * NE + col;
                    if (OUTF && in_f32) ((float*)Cp)[idx] = v2;
                    else                ((unsigned short*)Cp)[idx] = f2bf(v2);
                }
            }
        }
}

// Flash-style causal attention — R16 structure (validated R9, 44.3us steady):
//  * R12 compute core: 16x16x32 MFMA, swapped QK^T, cvt_pk P-pack, single
//    barrier/iter, K/V LDS double-buffer + 2-deep reg prefetch, T15
//    deferred-PV, setprio. 8 waves x 16 q-rows, block = 128 q-rows.
//  * T1 (b,h) grouping: XCD g = x%8 owns bh in {4g..4g+3} -> per-XCD K/V
//    2 MB L2-resident (validated R9: FETCH 58->12.8 MB; time-neutral ->
//    attn is NOT memory-bound; structural plateau ~44 us).
// 512 threads = 8 waves. Grid (16,16,2) = 512 blocks = 2 blocks/CU.
// ctx may alias qh: block reads only the q-rows it later writes.
__global__ __launch_bounds__(512, 4)
void attn(const unsigned short* qh, const unsigned short* kh,
          const unsigned short* vt, unsigned short* ctx)
{
    __shared__ __align__(16) unsigned short Ks[2][64 * 72];    // [buf][j][d], pad 72
    __shared__ __align__(16) unsigned short Vt[2][64 * 72];    // [buf][d][j], pad 72
    __shared__ __align__(16) unsigned short Ps[8][16 * 72];    // per-wave P, [i][j]
    const int t = threadIdx.x, w = t >> 6, l = t & 63;
    const int q = l >> 4, n = l & 15;
    const int half = w >> 2;
    // --- T1 XCD (b,h) grouping: XCD g = x%8 owns bh in {4g..4g+3} ---
    const int g = blockIdx.x & 7;
    const int b = g >> 2;
    const int h = (g & 3) * 4 + (blockIdx.y & 3);
    const int base_q = (blockIdx.y >> 2) | ((blockIdx.x >> 3) << 2);
    const int qb = blockIdx.z ? (15 - base_q) : base_q;  // z-flip: CU pair = 34 iters
    const int jtmax = 2 * qb + 1;        // block's last K/V tile
    const int qbe = 2 * qb + half;       // this wave's diag (last compute) tile
    const size_t base = (size_t)b * SEQ * NE + h * 64;
    const size_t vbase = (size_t)((b * 16 + h) * 64) << 11;   // vt[b][h][0][0]
    const int i0 = qb * 128 + w * 16;    // wave's 16 q-rows

    short8 qf[2];
    qf[0] = *(const short8*)(&qh[base + (size_t)(i0 + n) * NE + q * 8]);
    qf[1] = *(const short8*)(&qh[base + (size_t)(i0 + n) * NE + 32 + q * 8]);

    f32x4 o[4] = {};
    float lsp[4] = {0.f, 0.f, 0.f, 0.f};
    short8 pf_prev[2];     // previous tile's P fragments
    short8 vf_prev[8];     // previous tile's V fragments [ks*4+dt]

    const float K1 = 0.125f * 1.4426950408889634f;
    const float B2 = 24.0f * 1.4426950408889634f;

    // staging maps: 512 b128 chunks each for K and V^T, 1 per thread
    const int kr = t >> 3, kc = (t & 7) * 8;           // K: [row][8col]
    const int vd = t >> 3, vj = (t & 7) * 8;           // V^T: [d][8j]

    // prologue: tile 0 -> buf 0, prefetch tile 1 into regs (jtmax >= 1 always)
    short8 pk, pv;
    pk = *(const short8*)(&kh[base + (size_t)kr * NE + kc]);
    pv = *(const short8*)(&vt[vbase + ((size_t)vd << 11) + vj]);
    *(short8*)(&Ks[0][kr * 72 + kc]) = pk;
    *(short8*)(&Vt[0][vd * 72 + vj]) = pv;
    pk = *(const short8*)(&kh[base + (size_t)(64 + kr) * NE + kc]);
    pv = *(const short8*)(&vt[vbase + ((size_t)vd << 11) + 64 + vj]);
    __syncthreads();

    unsigned short* PsW = &Ps[w][0];
    int cur = 0;

    for (int jt = 0; jt <= jtmax; jt++) {
        // ---- drain prefetch regs (tile jt+1) into the idle buffer ----
        if (jt + 1 <= jtmax) {
            *(short8*)(&Ks[cur ^ 1][kr * 72 + kc]) = pk;
            *(short8*)(&Vt[cur ^ 1][vd * 72 + vj]) = pv;
        }
        // ---- issue tile jt+2 global loads (overlap with compute) ----
        if (jt + 2 <= jtmax) {
            const int jn = (jt + 2) * 64;
            pk = *(const short8*)(&kh[base + (size_t)(jn + kr) * NE + kc]);
            pv = *(const short8*)(&vt[vbase + ((size_t)vd << 11) + jn + vj]);
        }

        if (jt <= qbe) {    // wave-uniform; waves 0-3 skip the final tile
            const unsigned short* Kc = &Ks[cur][0];
            const unsigned short* Vc = &Vt[cur][0];

            // issue K-fragment reads first...
            short8 kf[2][4];
            #pragma unroll
            for (int ks = 0; ks < 2; ks++)
                #pragma unroll
                for (int nt = 0; nt < 4; nt++)
                    kf[ks][nt] = *(const short8*)(&Kc[(nt * 16 + n) * 72 + ks * 32 + q * 8]);

            // ...then the deferred PV of tile jt-1 (register-only; overlaps
            // the ds_read latency above on the MFMA pipe)
            if (jt > 0) {
                __builtin_amdgcn_s_setprio(1);
                #pragma unroll
                for (int ks = 0; ks < 2; ks++)
                    #pragma unroll
                    for (int dt = 0; dt < 4; dt++)
                        o[dt] = __builtin_amdgcn_mfma_f32_16x16x32_bf16(
                            pf_prev[ks], vf_prev[ks * 4 + dt], o[dt], 0, 0, 0);
                __builtin_amdgcn_s_setprio(0);
            }

            f32x4 sa[4] = {};
            __builtin_amdgcn_s_setprio(1);
            #pragma unroll
            for (int ks = 0; ks < 2; ks++)
                #pragma unroll
                for (int nt = 0; nt < 4; nt++)
                    // swapped: rows = j (k-index), cols = i (q-row)
                    sa[nt] = __builtin_amdgcn_mfma_f32_16x16x32_bf16(
                        kf[ks][nt], qf[ks], sa[nt], 0, 0, 0);
            __builtin_amdgcn_s_setprio(0);

            const bool diag = (jt == qbe);
            const int i = i0 + n;
            #pragma unroll
            for (int nt = 0; nt < 4; nt++) {
                float p[4];
                #pragma unroll
                for (int r = 0; r < 4; r++) {
                    float e = fmaf(sa[nt][r], K1, -B2);
                    if (diag) {
                        int j = jt * 64 + nt * 16 + q * 4 + r;
                        bool ok = (j < i) || (i == 0 && j == 0);
                        e = ok ? e : -256.0f;      // exp2(-256) == 0 exactly
                    }
                    p[r] = __builtin_amdgcn_exp2f(e);
                }
                lsp[nt] += (p[0] + p[1]) + (p[2] + p[3]);
                unsigned w0, w1;
                asm("v_cvt_pk_bf16_f32 %0, %1, %2" : "=v"(w0) : "v"(p[0]), "v"(p[1]));
                asm("v_cvt_pk_bf16_f32 %0, %1, %2" : "=v"(w1) : "v"(p[2]), "v"(p[3]));
                u32x2 wv; wv[0] = w0; wv[1] = w1;
                // P[i=n][j = nt*16 + q*4 .. +3] — one b64 per nt
                *(u32x2*)(&PsW[n * 72 + nt * 16 + q * 4]) = wv;
            }
            asm volatile("s_waitcnt lgkmcnt(0)" ::: "memory"); // Ps write->read (wave-private)

            // load NEXT-iteration operands: P frags + V frags into registers
            #pragma unroll
            for (int ks = 0; ks < 2; ks++)
                pf_prev[ks] = *(const short8*)(&PsW[n * 72 + ks * 32 + q * 8]);
            #pragma unroll
            for (int ks = 0; ks < 2; ks++)
                #pragma unroll
                for (int dt = 0; dt < 4; dt++)
                    vf_prev[ks * 4 + dt] =
                        *(const short8*)(&Vc[(dt * 16 + n) * 72 + ks * 32 + q * 8]);
        } else if (jt == qbe + 1) {
            // waves 0-3 flush their diag tile here (qbe+1 == jtmax)
            __builtin_amdgcn_s_setprio(1);
            #pragma unroll
            for (int ks = 0; ks < 2; ks++)
                #pragma unroll
                for (int dt = 0; dt < 4; dt++)
                    o[dt] = __builtin_amdgcn_mfma_f32_16x16x32_bf16(
                        pf_prev[ks], vf_prev[ks * 4 + dt], o[dt], 0, 0, 0);
            __builtin_amdgcn_s_setprio(0);
        }
        __syncthreads();   // single barrier: protects both buffers across swap
        cur ^= 1;
    }

    if (half) {   // waves 4-7 flush the final tile after the loop
        #pragma unroll
        for (int ks = 0; ks < 2; ks++)
            #pragma unroll
            for (int dt = 0; dt < 4; dt++)
                o[dt] = __builtin_amdgcn_mfma_f32_16x16x32_bf16(
                    pf_prev[ks], vf_prev[ks * 4 + dt], o[dt], 0, 0, 0);
    }

    // row sums: lane holds partial for row i = i0 + n; reduce across q-groups
    float ls = (lsp[0] + lsp[1]) + (lsp[2] + lsp[3]);
    ls += __shfl_xor(ls, 16, 64);
    ls += __shfl_xor(ls, 32, 64);

    #pragma unroll
    for (int r = 0; r < 4; r++) {
        float inv = 1.0f / __shfl(ls, q * 4 + r, 64);   // total for row i0+q*4+r
        #pragma unroll
        for (int dt = 0; dt < 4; dt++)
            ctx[base + (size_t)(i0 + q * 4 + r) * NE + dt * 16 + n] =
                f2bf(o[dt][r] * inv);
    }
}

extern "C" void kernel_launch(void* const* d_in, const int* in_sizes, int n_in,
                              void* d_out, int out_size, void* d_ws, size_t ws_size,
                              hipStream_t stream) {
    const void* q  = d_in[0];
    const void* k  = d_in[1];
    const void* v  = d_in[2];
    const void* Wq = d_in[3];
    const void* Wk = d_in[4];
    const void* Wv = d_in[5];
    const void* bv = d_in[6];
    const void* Wo = d_in[7];
    const void* bo = d_in[8];

    const size_t MB = 1024 * 1024;
    const size_t M4 = 4 * MB;   // 4M shorts = 8 MB
    unsigned short* ws = (unsigned short*)d_ws;
    unsigned short* qh  = ws;               // [2,2048,1024] bf16
    unsigned short* kh  = ws + 1 * M4;      // [2,2048,1024] bf16
    unsigned short* vt  = ws + 2 * M4;      // [2,16,64,2048] bf16 (V transposed)
    unsigned short* ctx = qh;               // safe alias (see attn)

    int tier = (ws_size >= 56 * MB + 64) ? 2 : (ws_size >= 32 * MB + 64) ? 1 : 0;

    unsigned short *qc, *kc, *vc, *Wqc, *Wkc, *Wvc, *Woc;
    int* flag;
    if (tier == 2) {
        qc = ws + 3 * M4; kc = ws + 4 * M4; vc = ws + 5 * M4;
        Wqc = ws + 6 * M4;           Wkc = Wqc + 1 * MB;
        Wvc = Wqc + 2 * MB;          Woc = Wqc + 3 * MB;
        flag = (int*)((char*)d_ws + 56 * MB);
    } else if (tier == 1) {
        qc = kc = vc = nullptr;
        Wqc = ws + 3 * M4;           Wkc = Wqc + 1 * MB;
        Wvc = Wqc + 2 * MB;          Woc = Wqc + 3 * MB;
        flag = (int*)((char*)d_ws + 32 * MB);
    } else {
        qc = kc = vc = nullptr; Wqc = Wkc = Wvc = Woc = nullptr;
        flag = (int*)((char*)d_ws + 24 * MB);
    }

    detect_dtype<<<1, 256, 0, stream>>>((const unsigned short*)q, flag);

    if (tier > 0) {
        Ptrs7 p;
        p.s[0] = q;  p.s[1] = k;  p.s[2] = v;
        p.s[3] = Wq; p.s[4] = Wk; p.s[5] = Wv; p.s[6] = Wo;
        p.d[0] = qc; p.d[1] = kc; p.d[2] = vc;
        p.d[3] = Wqc; p.d[4] = Wkc; p.d[5] = Wvc; p.d[6] = Woc;
        if (tier == 2)
            convert7<<<dim3(1024, 1, 7), 256, 0, stream>>>(p, flag, 0);
        else
            convert7<<<dim3(1024, 1, 4), 256, 0, stream>>>(p, flag, 3);
    }

    if (tier == 2)
        gemm_bt<1, 1, 0, 1><<<dim3(8, 32, 3), 256, 0, stream>>>(
            qc, kc, vc, Wqc, Wkc, Wvc, nullptr, nullptr, bv, qh, kh, vt, flag);
    else if (tier == 1)
        gemm_bt<0, 1, 0, 1><<<dim3(8, 32, 3), 256, 0, stream>>>(
            q, k, v, Wqc, Wkc, Wvc, nullptr, nullptr, bv, qh, kh, vt, flag);
    else
        gemm_bt<0, 0, 0, 1><<<dim3(8, 32, 3), 256, 0, stream>>>(
            q, k, v, Wq, Wk, Wv, nullptr, nullptr, bv, qh, kh, vt, flag);

    attn<<<dim3(16, 16, 2), 512, 0, stream>>>(qh, kh, vt, ctx);

    // output GEMM R17: 64x64 tiles -> grid (16,64) = 1024 blocks = 4 blocks/CU
    if (tier > 0)
        gemm_bt<1, 1, 1, 0, 64, 64, 4><<<dim3(16, 64, 1), 256, 0, stream>>>(
            ctx, ctx, ctx, Woc, Woc, Woc, bo, bo, bo, d_out, d_out, d_out, flag);
    else
        gemm_bt<1, 0, 1, 0, 64, 64, 4><<<dim3(16, 64, 1), 256, 0, stream>>>(
            ctx, ctx, ctx, Wo, Wo, Wo, bo, bo, bo, d_out, d_out, d_out, flag);
}